// Round 2
// baseline (215.749 us; speedup 1.0000x reference)
//
#include <hip/hip_runtime.h>

// Histogram2D: x (16, 131072, 2) f32 in [0,1) -> counts (16, 100, 100) f32, normalized.
// Round 1: (a) 11-site candidate window (3x3 core + side-selected +/-2 paired with the
// other coord's own bin) instead of 25 masked sites; (b) non-atomic flush of per-block
// LDS partials into d_ws + per-batch totals, then a fused reduce+normalize kernel.
// Fallback to global-atomic flush if ws is too small.

#define BINS     100
#define NBINS2   (BINS * BINS)     // 10000
#define NPOINTS  131072
#define NBATCH   16
#define PPB      32                // partial blocks per batch
#define CHUNK    (NPOINTS / PPB)   // 4096 points per block
#define THREADS  1024
#define NPART    (NBATCH * PPB)    // 512

// ---- shared inner loop: accumulate one point's contributions into LDS hist ----
__device__ __forceinline__ float cand_d(float xx, int n) {
    // center = DELTA * (n + 0.5), single-rounded; invalid neighbor -> 1e9 (w<0, skipped)
    const float c = __fmul_rn(0.01f, (float)n + 0.5f);
    const float d = fabsf(__fsub_rn(xx, c));
    return ((unsigned)n < (unsigned)BINS) ? d : 1e9f;
}

__device__ __forceinline__ void accum_point(float* __restrict__ lh, float x0, float x1) {
    // own bin: floor(x / DELTA) with IEEE f32 division (matches numpy), clipped
    int i0 = (int)floorf(__fdiv_rn(x0, 0.01f)); i0 = min(max(i0, 0), BINS - 1);
    int i1 = (int)floorf(__fdiv_rn(x1, 0.01f)); i1 = min(max(i1, 0), BINS - 1);
    const float c0 = __fmul_rn(0.01f, (float)i0 + 0.5f);
    const float c1 = __fmul_rn(0.01f, (float)i1 + 0.5f);
    // the only +/-2 offset that can ever fire is on the side the point leans toward
    const int f0 = (x0 > c0) ? i0 + 2 : i0 - 2;
    const int f1 = (x1 > c1) ? i1 + 2 : i1 - 2;

    float e0[4], e1[4];
    int   r0[4], cc1[4];
    r0[0] = (i0 - 1) * BINS; e0[0] = cand_d(x0, i0 - 1);
    r0[1] = i0 * BINS;       e0[1] = fabsf(__fsub_rn(x0, c0));
    r0[2] = (i0 + 1) * BINS; e0[2] = cand_d(x0, i0 + 1);
    r0[3] = f0 * BINS;       e0[3] = cand_d(x0, f0);
    cc1[0] = i1 - 1;         e1[0] = cand_d(x1, i1 - 1);
    cc1[1] = i1;             e1[1] = fabsf(__fsub_rn(x1, c1));
    cc1[2] = i1 + 1;         e1[2] = cand_d(x1, i1 + 1);
    cc1[3] = f1;             e1[3] = cand_d(x1, f1);

    #pragma unroll
    for (int a = 0; a < 3; ++a) {
        #pragma unroll
        for (int b2 = 0; b2 < 3; ++b2) {
            const float w = __fsub_rn(0.01f, __fmul_rn(0.5f, __fadd_rn(e0[a], e1[b2])));
            if (w > 0.0f) atomicAdd(&lh[r0[a] + cc1[b2]], w);
        }
    }
    {   // (far0, own1)
        const float w = __fsub_rn(0.01f, __fmul_rn(0.5f, __fadd_rn(e0[3], e1[1])));
        if (w > 0.0f) atomicAdd(&lh[r0[3] + cc1[1]], w);
    }
    {   // (own0, far1)
        const float w = __fsub_rn(0.01f, __fmul_rn(0.5f, __fadd_rn(e0[1], e1[3])));
        if (w > 0.0f) atomicAdd(&lh[r0[1] + cc1[3]], w);
    }
}

// ---- main path: partials into ws, per-batch totals via 16 wave atomics/block ----
__global__ __launch_bounds__(THREADS) void hist_part_kernel(
    const float* __restrict__ x, float* __restrict__ part, float* __restrict__ totals)
{
    __shared__ float lh[NBINS2];
    for (int i = threadIdx.x; i < NBINS2; i += THREADS) lh[i] = 0.0f;
    __syncthreads();

    const int b  = blockIdx.x / PPB;
    const int pb = blockIdx.x % PPB;
    const float4* __restrict__ xp = reinterpret_cast<const float4*>(
        x + (size_t)b * (NPOINTS * 2) + (size_t)pb * (CHUNK * 2));

    #pragma unroll
    for (int k = 0; k < (CHUNK / 2) / THREADS; ++k) {
        const float4 p = xp[threadIdx.x + k * THREADS];
        accum_point(lh, p.x, p.y);
        accum_point(lh, p.z, p.w);
    }
    __syncthreads();

    float* __restrict__ po = part + (size_t)blockIdx.x * NBINS2;
    float ts = 0.0f;
    for (int i = threadIdx.x; i < NBINS2; i += THREADS) {
        const float v = lh[i];
        po[i] = v;
        ts += v;
    }
    #pragma unroll
    for (int off = 32; off > 0; off >>= 1) ts += __shfl_down(ts, off, 64);
    if ((threadIdx.x & 63) == 0) unsafeAtomicAdd(&totals[b], ts);
}

// 160 blocks: batch b = blk/10, 1000-bin chunk q = blk%10. Sum 32 partials + normalize.
__global__ __launch_bounds__(1024) void reduce_norm_kernel(
    const float* __restrict__ part, const float* __restrict__ totals,
    float* __restrict__ out)
{
    const int b = blockIdx.x / 10;
    const int q = blockIdx.x % 10;
    if (threadIdx.x < 1000) {
        const int bin = q * 1000 + threadIdx.x;
        const float* __restrict__ pb = part + (size_t)b * PPB * NBINS2 + bin;
        float s = 0.0f;
        #pragma unroll
        for (int p = 0; p < PPB; ++p) s = __fadd_rn(s, pb[(size_t)p * NBINS2]);
        out[b * NBINS2 + bin] = __fdiv_rn(s, __fadd_rn(totals[b], 1e-5f));
    }
}

// ---- fallback path (ws too small): atomic flush into out + separate norm ----
__global__ __launch_bounds__(THREADS) void hist_accum_kernel(
    const float* __restrict__ x, float* __restrict__ out)
{
    __shared__ float lh[NBINS2];
    for (int i = threadIdx.x; i < NBINS2; i += THREADS) lh[i] = 0.0f;
    __syncthreads();

    const int b  = blockIdx.x / PPB;
    const int pb = blockIdx.x % PPB;
    const float4* __restrict__ xp = reinterpret_cast<const float4*>(
        x + (size_t)b * (NPOINTS * 2) + (size_t)pb * (CHUNK * 2));

    #pragma unroll
    for (int k = 0; k < (CHUNK / 2) / THREADS; ++k) {
        const float4 p = xp[threadIdx.x + k * THREADS];
        accum_point(lh, p.x, p.y);
        accum_point(lh, p.z, p.w);
    }
    __syncthreads();

    float* __restrict__ ob = out + (size_t)b * NBINS2;
    for (int i = threadIdx.x; i < NBINS2; i += THREADS) {
        const float v = lh[i];
        if (v != 0.0f) unsafeAtomicAdd(&ob[i], v);
    }
}

__global__ __launch_bounds__(1024) void norm_kernel(float* __restrict__ out)
{
    const int b = blockIdx.x;
    float* __restrict__ h = out + (size_t)b * NBINS2;
    float local = 0.0f;
    for (int i = threadIdx.x; i < NBINS2; i += 1024) local += h[i];
    #pragma unroll
    for (int off = 32; off > 0; off >>= 1) local += __shfl_down(local, off, 64);

    __shared__ float wsum[16];
    __shared__ float sden;
    const int wid  = threadIdx.x >> 6;
    const int lane = threadIdx.x & 63;
    if (lane == 0) wsum[wid] = local;
    __syncthreads();
    if (threadIdx.x == 0) {
        float t = 0.0f;
        #pragma unroll
        for (int i = 0; i < 16; ++i) t += wsum[i];
        sden = __fadd_rn(t, 1e-5f);
    }
    __syncthreads();
    const float den = sden;
    for (int i = threadIdx.x; i < NBINS2; i += 1024) h[i] = __fdiv_rn(h[i], den);
}

extern "C" void kernel_launch(void* const* d_in, const int* in_sizes, int n_in,
                              void* d_out, int out_size, void* d_ws, size_t ws_size,
                              hipStream_t stream) {
    (void)in_sizes; (void)n_in;
    const float* x = (const float*)d_in[0];
    float* out = (float*)d_out;

    const size_t need = 64 + (size_t)NPART * NBINS2 * sizeof(float) + NBATCH * sizeof(float);
    if (ws_size >= need) {
        float* totals = (float*)d_ws;                      // [16] at ws+0
        float* part   = (float*)((char*)d_ws + 64);        // [512][10000], 64B-aligned rows
        hipMemsetAsync(totals, 0, NBATCH * sizeof(float), stream);
        hist_part_kernel<<<NPART, THREADS, 0, stream>>>(x, part, totals);
        reduce_norm_kernel<<<NBATCH * 10, 1024, 0, stream>>>(part, totals, out);
    } else {
        hipMemsetAsync(out, 0, (size_t)out_size * sizeof(float), stream);
        hist_accum_kernel<<<NPART, THREADS, 0, stream>>>(x, out);
        norm_kernel<<<NBATCH, 1024, 0, stream>>>(out);
    }
}